// Round 13
// baseline (307.094 us; speedup 1.0000x reference)
//
#include <hip/hip_runtime.h>

#define NN 8192
#define FIN 256
#define FOUT 128
#define BKJ 128            /* j per step */
#define JSPLIT 8
#define LALPHA 0.2f
#define NEGB -9.0e15f
#define LOG2E 1.4426950408889634f

typedef short bf16x8 __attribute__((ext_vector_type(8)));
typedef float f32x4 __attribute__((ext_vector_type(4)));

#define FOR8(X) X(0) X(1) X(2) X(3) X(4) X(5) X(6) X(7)

static __device__ __forceinline__ unsigned short f2bf(float f) {
    unsigned u = __float_as_uint(f);
    u += 0x7FFFu + ((u >> 16) & 1u);   // RNE
    return (unsigned short)(u >> 16);
}
static __device__ __forceinline__ float ex2(float x) {
    float r; asm("v_exp_f32 %0, %1" : "=v"(r) : "v"(x)); return r;
}
static __device__ __forceinline__ int cvtpk(float lo, float hi) {
    int r; asm("v_cvt_pk_bf16_f32 %0, %1, %2" : "=v"(r) : "v"(lo), "v"(hi)); return r;
}

// ---------------- K1: Wh = h@W (f32), si = Wh@a1, sj = Wh@a2 (+sjl = sj*log2e), WhT bf16 ----------------
__global__ __launch_bounds__(256) void gat_k1(
    const float* __restrict__ h, const float* __restrict__ W,
    const float* __restrict__ a, unsigned short* __restrict__ WhT,
    float* __restrict__ si, float* __restrict__ sj, float* __restrict__ sjl)
{
    __shared__ float Wt[64 * 128];          // 32 KB: W chunk [64k][128c]
    __shared__ float hT[64 * 36 + 4];       // 9 KB: h chunk transposed [64k][32r] pad 36
    const int t = threadIdx.x;
    const int r0 = blockIdx.x * 32;
    const int rg = t >> 5;    // rows rg*4..+4
    const int cg = t & 31;    // cols cg*4..+4
    float acc[4][4] = {{0.f,0.f,0.f,0.f},{0.f,0.f,0.f,0.f},{0.f,0.f,0.f,0.f},{0.f,0.f,0.f,0.f}};

    for (int kc = 0; kc < 4; ++kc) {
        __syncthreads();
        const float4* Ws = (const float4*)(W + kc * 64 * FOUT);
        float4* Wd = (float4*)Wt;
        #pragma unroll
        for (int v = 0; v < 8; ++v) Wd[v * 256 + t] = Ws[v * 256 + t];
        {
            const int hr = t >> 3, hk = (t & 7) * 8;
            const float* hs = h + (size_t)(r0 + hr) * FIN + kc * 64 + hk;
            float4 x0 = *(const float4*)hs;
            float4 x1 = *(const float4*)(hs + 4);
            hT[(hk + 0) * 36 + hr] = x0.x; hT[(hk + 1) * 36 + hr] = x0.y;
            hT[(hk + 2) * 36 + hr] = x0.z; hT[(hk + 3) * 36 + hr] = x0.w;
            hT[(hk + 4) * 36 + hr] = x1.x; hT[(hk + 5) * 36 + hr] = x1.y;
            hT[(hk + 6) * 36 + hr] = x1.z; hT[(hk + 7) * 36 + hr] = x1.w;
        }
        __syncthreads();
        #pragma unroll 8
        for (int kk = 0; kk < 64; ++kk) {
            float4 hv4 = *(const float4*)&hT[kk * 36 + rg * 4];
            float4 wv4 = *(const float4*)&Wt[kk * 128 + cg * 4];
            float hv[4] = {hv4.x, hv4.y, hv4.z, hv4.w};
            float wv[4] = {wv4.x, wv4.y, wv4.z, wv4.w};
            #pragma unroll
            for (int rr = 0; rr < 4; ++rr)
                #pragma unroll
                for (int cc = 0; cc < 4; ++cc)
                    acc[rr][cc] = fmaf(hv[rr], wv[cc], acc[rr][cc]);
        }
    }
    float4 a1v4 = *(const float4*)(a + cg * 4);
    float4 a2v4 = *(const float4*)(a + FOUT + cg * 4);
    float a1v[4] = {a1v4.x, a1v4.y, a1v4.z, a1v4.w};
    float a2v[4] = {a2v4.x, a2v4.y, a2v4.z, a2v4.w};
    float ps[4], qs[4];
    #pragma unroll
    for (int rr = 0; rr < 4; ++rr) {
        float p = 0.f, q = 0.f;
        #pragma unroll
        for (int cc = 0; cc < 4; ++cc) {
            p = fmaf(acc[rr][cc], a1v[cc], p);
            q = fmaf(acc[rr][cc], a2v[cc], q);
        }
        ps[rr] = p; qs[rr] = q;
    }
    #pragma unroll
    for (int off = 1; off <= 16; off <<= 1) {
        #pragma unroll
        for (int rr = 0; rr < 4; ++rr) {
            ps[rr] += __shfl_xor(ps[rr], off);
            qs[rr] += __shfl_xor(qs[rr], off);
        }
    }
    if (cg == 0) {
        #pragma unroll
        for (int rr = 0; rr < 4; ++rr) {
            si[r0 + rg * 4 + rr] = ps[rr];
            sj[r0 + rg * 4 + rr] = qs[rr];
            sjl[r0 + rg * 4 + rr] = qs[rr] * LOG2E;
        }
    }
    #pragma unroll
    for (int cc = 0; cc < 4; ++cc) {
        ushort4 v;
        v.x = f2bf(acc[0][cc]); v.y = f2bf(acc[1][cc]);
        v.z = f2bf(acc[2][cc]); v.w = f2bf(acc[3][cc]);
        *(ushort4*)(WhT + (size_t)(cg * 4 + cc) * NN + r0 + rg * 4) = v;
    }
}

// ---------------- K1s: sjmax = max_j sj[j] (global, one scalar) ----------------
__global__ __launch_bounds__(256) void gat_k1s(
    const float* __restrict__ sj, float* __restrict__ sjmax)
{
    __shared__ float red[256];
    float m = -1e30f;
    for (int i = threadIdx.x; i < NN; i += 256) m = fmaxf(m, sj[i]);
    red[threadIdx.x] = m;
    __syncthreads();
    for (int o = 128; o > 0; o >>= 1) {
        if (threadIdx.x < o) red[threadIdx.x] = fmaxf(red[threadIdx.x], red[threadIdx.x + o]);
        __syncthreads();
    }
    if (threadIdx.x == 0) sjmax[0] = red[0];
}

// ---------------- K2: fixed-m masked softmax (exp2, LDS bitmask) + P@Wh via MFMA ----------------
// Block prologue streams its 64-row adj panel row-contiguously -> ballot -> LDS bitmask.
// Main loop: zero global loads on the critical path (mask+sjl from LDS, WhT stg prefetched).
static __device__ __forceinline__ float pe(unsigned bit, float sjlv, float a2, float b2) {
    float t1 = a2 + sjlv;
    float t2 = fmaf(0.2f, sjlv, b2);
    float y = fmaxf(t1, t2);
    y = bit ? y : NEGB;           // 2^NEGB -> 0
    return ex2(y);
}

template<int JS, bool FINAL>
__global__ __launch_bounds__(256, 2) void gat_k2(
    const int* __restrict__ adj, const unsigned short* __restrict__ WhT,
    const float* __restrict__ si, const float* __restrict__ sjl,
    const float* __restrict__ sjmaxp,
    float* __restrict__ lsum, float* __restrict__ Opart, float* __restrict__ out)
{
    const int JR_ = NN / JS;                 // j per split
    const int NST_ = JR_ / BKJ;              // steps
    const int MDW = JR_ / 32 + 4;            // mask dwords per row (padded: +4 keeps %32 spread)
    __shared__ __align__(16) unsigned short tile[16384];         // 32 KB WhT tile [128c][128j], swizzled
    __shared__ __align__(16) unsigned int   mask_lds[64 * (NN / JS / 32 + 4)];
    __shared__ __align__(16) float          sjl_lds[NN / JS];
    const int t = threadIdx.x;
    const int w = t >> 6, l = t & 63;
    const int rb = (int)blockIdx.x / JS, js = (int)blockIdx.x % JS;
    const int iw = rb * 64 + w * 16;       // wave's 16 rows
    const int j0 = js * JR_;
    const int row = l & 15, kg = l >> 4;   // MFMA A-frag: row = l&15, k-slice = kg*8..+8
    const int kg8 = kg * 8;

    const float si_l = si[iw + row];
    const float sjmax = sjmaxp[0];
    const float xm = si_l + sjmax;
    const float m_row = fmaxf(xm, LALPHA * xm);   // upper bound on every masked score of this row
    const float a2 = (si_l - m_row) * LOG2E;
    const float b2 = (LALPHA * si_l - m_row) * LOG2E;

    // ---- prologue 1: sjl slice -> LDS (coalesced float4) ----
    for (int i = t * 4; i < JR_; i += 1024)
        *(float4*)&sjl_lds[i] = *(const float4*)(sjl + j0 + i);

    // ---- prologue 2: adj panel -> bitmask in LDS (row-contiguous streaming + ballot) ----
    // wave w packs its own rows w*16+r; chunk c covers j = c*64 + lane.
    for (int r = 0; r < 16; ++r) {
        const int lrow = w * 16 + r;
        const int* arow = adj + (size_t)(rb * 64 + lrow) * NN + j0;
        unsigned long long* mq = (unsigned long long*)&mask_lds[lrow * MDW];
        #pragma unroll
        for (int c = 0; c < JR_ / 64; ++c) {
            int v = arow[c * 64 + l];
            unsigned long long m = __ballot(v > 0);
            if (l == 0) mq[c] = m;
        }
    }

    // ---- prologue 3: first WhT stage loads ----
#define GSRC_D(v) const unsigned short* gsrc##v = WhT + (size_t)(v * 16 + (t >> 4)) * NN + j0 + (t & 15) * 8; \
                  const int ldo##v = ((v * 256 + t) * 16) ^ (((t >> 4) & 7) << 4);
    FOR8(GSRC_D)
#define REG_D(v) int4 stg##v;
    FOR8(REG_D)
#define STG_L0(v) stg##v = *(const int4*)(gsrc##v);
    FOR8(STG_L0)

#define ACC_D(n) f32x4 acc##n = {0.f, 0.f, 0.f, 0.f};
    FOR8(ACC_D)
    f32x4 acc8 = {0.f, 0.f, 0.f, 0.f};    // row-sum accumulator (ones-MFMA)
    bf16x8 ones;
    #pragma unroll
    for (int z = 0; z < 8; ++z) ones[z] = (short)0x3F80;   // bf16 1.0
    const int kg16 = kg * 16;
    const unsigned int* mrow = &mask_lds[(w * 16 + row) * MDW];

    __syncthreads();   // masks + sjl visible to all (wave-local really, but tile loop needs sync anyway)

#define STG_WR(v) *(int4*)((char*)tile + ldo##v) = stg##v;
#define STG_LN(v) stg##v = *(const int4*)(gsrc##v + so);
#define P8(AF, MW, off) { \
    float4 s0_ = *(const float4*)&sjl_lds[(off)]; float4 s1_ = *(const float4*)&sjl_lds[(off) + 4]; \
    const unsigned sh_ = (MW) >> kg8; \
    float p0_ = pe((sh_ >> 0) & 1u, s0_.x, a2, b2), p1_ = pe((sh_ >> 1) & 1u, s0_.y, a2, b2); \
    float p2_ = pe((sh_ >> 2) & 1u, s0_.z, a2, b2), p3_ = pe((sh_ >> 3) & 1u, s0_.w, a2, b2); \
    float p4_ = pe((sh_ >> 4) & 1u, s1_.x, a2, b2), p5_ = pe((sh_ >> 5) & 1u, s1_.y, a2, b2); \
    float p6_ = pe((sh_ >> 6) & 1u, s1_.z, a2, b2), p7_ = pe((sh_ >> 7) & 1u, s1_.w, a2, b2); \
    int4 w_; w_.x = cvtpk(p0_, p1_); w_.y = cvtpk(p2_, p3_); \
    w_.z = cvtpk(p4_, p5_); w_.w = cvtpk(p6_, p7_); \
    AF = __builtin_bit_cast(bf16x8, w_); }
#define MFMA_ROW(n) { const int c_ = n * 16 + row; \
    const int off_ = c_ * 256 + ((KB ^ ((c_ & 7) << 4))); \
    bf16x8 bv_ = *(const bf16x8*)((const char*)tile + off_); \
    acc##n = __builtin_amdgcn_mfma_f32_16x16x32_bf16(AFk, bv_, acc##n, 0, 0, 0); }
#define MFMA_KC(afv, kcl) { const bf16x8 AFk = afv; const int KB = kcl * 64 + kg16; FOR8(MFMA_ROW) \
    acc8 = __builtin_amdgcn_mfma_f32_16x16x32_bf16(AFk, ones, acc8, 0, 0, 0); }

#define BARRIER() { __builtin_amdgcn_sched_barrier(0); \
    asm volatile("s_waitcnt lgkmcnt(0)" ::: "memory"); \
    __builtin_amdgcn_s_barrier(); \
    __builtin_amdgcn_sched_barrier(0); }

    for (int s = 0; s < NST_; ++s) {
        // A: write staged WhT tile (swizzled b128 writes) + read this step's mask window
        FOR8(STG_WR)
        uint4 mi = *(const uint4*)(mrow + s * 4);
        // bar A: tile visible to all waves (lgkm-only; stg prefetches stay in flight)
        BARRIER()
        // B: scores -> p (bf16); all inputs from LDS/regs
        bf16x8 af0, af1, af2, af3;
        {
            const int off = s * BKJ + kg8;
            P8(af0, mi.x, off)
            P8(af1, mi.y, off + 32)
            P8(af2, mi.z, off + 64)
            P8(af3, mi.w, off + 96)
        }
        // C: issue next WhT stage loads (L2; consumed at next STG_WR)
        if (s + 1 < NST_) {
            const size_t so = (size_t)(s + 1) * BKJ;
            FOR8(STG_LN)
        }
        // D: MFMA 4 k-chunks x (8 col-tiles + 1 ones row-sum)
        MFMA_KC(af0, 0) MFMA_KC(af1, 1) MFMA_KC(af2, 2) MFMA_KC(af3, 3)
        // bar B: all waves' tile reads done; next iteration may overwrite
        BARRIER()
    }

    // acc8[q] = rowsum for row iw + kg*4 + q (identical across the 16 col-lanes)
    if (FINAL) {
#define FN_ROW(n) { size_t ob = (size_t)(iw + kg * 4) * FOUT + n * 16 + row; \
    float o0 = acc##n[0] / acc8[0]; out[ob]            = (o0 > 0.f) ? o0 : expm1f(o0); \
    float o1 = acc##n[1] / acc8[1]; out[ob + FOUT]     = (o1 > 0.f) ? o1 : expm1f(o1); \
    float o2 = acc##n[2] / acc8[2]; out[ob + 2 * FOUT] = (o2 > 0.f) ? o2 : expm1f(o2); \
    float o3 = acc##n[3] / acc8[3]; out[ob + 3 * FOUT] = (o3 > 0.f) ? o3 : expm1f(o3); }
        FOR8(FN_ROW)
    } else {
        if (row == 0) {
            #pragma unroll
            for (int q = 0; q < 4; ++q)
                lsum[(size_t)js * NN + iw + kg * 4 + q] = acc8[q];
        }
#define ST_ROW(n) { size_t ob = ((size_t)js * NN + iw + kg * 4) * FOUT + n * 16 + row; \
    Opart[ob] = acc##n[0]; Opart[ob + FOUT] = acc##n[1]; \
    Opart[ob + 2 * FOUT] = acc##n[2]; Opart[ob + 3 * FOUT] = acc##n[3]; }
        FOR8(ST_ROW)
    }
}

// ---------------- K3: merge j-splits (plain sums; shared fixed m), divide, ELU ----------------
__global__ __launch_bounds__(256) void gat_k3(
    const float* __restrict__ lsum, const float* __restrict__ Opart,
    float* __restrict__ out)
{
    const int t = threadIdx.x;
    const int i = (int)blockIdx.x * 2 + (t >> 7);
    const int f = t & 127;
    float den = 0.f, num = 0.f;
    const size_t SP = (size_t)NN * FOUT;
    size_t base = (size_t)i * FOUT + f;
    #pragma unroll
    for (int k = 0; k < JSPLIT; ++k) {
        den += lsum[(size_t)k * NN + i];
        num += Opart[(size_t)k * SP + base];
    }
    float o = num / den;
    out[base] = (o > 0.f) ? o : expm1f(o);   // ELU, alpha=1
}

extern "C" void kernel_launch(void* const* d_in, const int* in_sizes, int n_in,
                              void* d_out, int out_size, void* d_ws, size_t ws_size,
                              hipStream_t stream) {
    const float* h  = (const float*)d_in[0];
    const int*  adj = (const int*)d_in[1];
    const float* W  = (const float*)d_in[2];
    const float* a  = (const float*)d_in[3];
    float* out = (float*)d_out;
    char* ws = (char*)d_ws;
    // ws: WhT 2MB | si 32KB | sj 32KB | sjl 32KB | sjmax 256B | lsum 8*32KB | Opart 8*4MB
    unsigned short* WhT = (unsigned short*)ws;
    float* si     = (float*)(ws + 2097152);
    float* sj     = (float*)(ws + 2129920);
    float* sjl    = (float*)(ws + 2162688);
    float* sjmax  = (float*)(ws + 2195456);
    float* lsum   = (float*)(ws + 2195712);
    float* Opart  = (float*)(ws + 2457856);
    const size_t need = 2457856 + (size_t)JSPLIT * NN * FOUT * 4;   // ~36 MB

    gat_k1<<<256, 256, 0, stream>>>(h, W, a, WhT, si, sj, sjl);
    gat_k1s<<<1, 256, 0, stream>>>(sj, sjmax);
    if (ws_size >= need) {
        gat_k2<JSPLIT, false><<<128 * JSPLIT, 256, 0, stream>>>(adj, WhT, si, sjl, sjmax, lsum, Opart, out);
        gat_k3<<<4096, 256, 0, stream>>>(lsum, Opart, out);
    } else {
        gat_k2<1, true><<<128, 256, 0, stream>>>(adj, WhT, si, sjl, sjmax, lsum, Opart, out);
    }
}

// Round 14
// 103.223 us; speedup vs baseline: 2.9751x; 2.9751x over previous
//
#include <hip/hip_runtime.h>

#define NN 8192
#define FIN 256
#define FOUT 128
#define BKJ 128            /* j per step */
#define JSPLIT 4
#define LALPHA 0.2f
#define NEGB -9.0e15f
#define LOG2E 1.4426950408889634f

typedef short bf16x8 __attribute__((ext_vector_type(8)));
typedef float f32x4 __attribute__((ext_vector_type(4)));

#define FOR8(X) X(0) X(1) X(2) X(3) X(4) X(5) X(6) X(7)

static __device__ __forceinline__ unsigned short f2bf(float f) {
    unsigned u = __float_as_uint(f);
    u += 0x7FFFu + ((u >> 16) & 1u);   // RNE
    return (unsigned short)(u >> 16);
}
static __device__ __forceinline__ float ex2(float x) {
    float r; asm("v_exp_f32 %0, %1" : "=v"(r) : "v"(x)); return r;
}
static __device__ __forceinline__ int cvtpk(float lo, float hi) {
    int r; asm("v_cvt_pk_bf16_f32 %0, %1, %2" : "=v"(r) : "v"(lo), "v"(hi)); return r;
}

// ---------------- K1: Wh = h@W (f32), si = Wh@a1, sj = Wh@a2 (+sjl = sj*log2e), WhT bf16 ----------------
__global__ __launch_bounds__(256) void gat_k1(
    const float* __restrict__ h, const float* __restrict__ W,
    const float* __restrict__ a, unsigned short* __restrict__ WhT,
    float* __restrict__ si, float* __restrict__ sj, float* __restrict__ sjl)
{
    __shared__ float Wt[64 * 128];          // 32 KB: W chunk [64k][128c]
    __shared__ float hT[64 * 36 + 4];       // 9 KB: h chunk transposed [64k][32r] pad 36
    const int t = threadIdx.x;
    const int r0 = blockIdx.x * 32;
    const int rg = t >> 5;    // rows rg*4..+4
    const int cg = t & 31;    // cols cg*4..+4
    float acc[4][4] = {{0.f,0.f,0.f,0.f},{0.f,0.f,0.f,0.f},{0.f,0.f,0.f,0.f},{0.f,0.f,0.f,0.f}};

    for (int kc = 0; kc < 4; ++kc) {
        __syncthreads();
        const float4* Ws = (const float4*)(W + kc * 64 * FOUT);
        float4* Wd = (float4*)Wt;
        #pragma unroll
        for (int v = 0; v < 8; ++v) Wd[v * 256 + t] = Ws[v * 256 + t];
        {
            const int hr = t >> 3, hk = (t & 7) * 8;
            const float* hs = h + (size_t)(r0 + hr) * FIN + kc * 64 + hk;
            float4 x0 = *(const float4*)hs;
            float4 x1 = *(const float4*)(hs + 4);
            hT[(hk + 0) * 36 + hr] = x0.x; hT[(hk + 1) * 36 + hr] = x0.y;
            hT[(hk + 2) * 36 + hr] = x0.z; hT[(hk + 3) * 36 + hr] = x0.w;
            hT[(hk + 4) * 36 + hr] = x1.x; hT[(hk + 5) * 36 + hr] = x1.y;
            hT[(hk + 6) * 36 + hr] = x1.z; hT[(hk + 7) * 36 + hr] = x1.w;
        }
        __syncthreads();
        #pragma unroll 8
        for (int kk = 0; kk < 64; ++kk) {
            float4 hv4 = *(const float4*)&hT[kk * 36 + rg * 4];
            float4 wv4 = *(const float4*)&Wt[kk * 128 + cg * 4];
            float hv[4] = {hv4.x, hv4.y, hv4.z, hv4.w};
            float wv[4] = {wv4.x, wv4.y, wv4.z, wv4.w};
            #pragma unroll
            for (int rr = 0; rr < 4; ++rr)
                #pragma unroll
                for (int cc = 0; cc < 4; ++cc)
                    acc[rr][cc] = fmaf(hv[rr], wv[cc], acc[rr][cc]);
        }
    }
    float4 a1v4 = *(const float4*)(a + cg * 4);
    float4 a2v4 = *(const float4*)(a + FOUT + cg * 4);
    float a1v[4] = {a1v4.x, a1v4.y, a1v4.z, a1v4.w};
    float a2v[4] = {a2v4.x, a2v4.y, a2v4.z, a2v4.w};
    float ps[4], qs[4];
    #pragma unroll
    for (int rr = 0; rr < 4; ++rr) {
        float p = 0.f, q = 0.f;
        #pragma unroll
        for (int cc = 0; cc < 4; ++cc) {
            p = fmaf(acc[rr][cc], a1v[cc], p);
            q = fmaf(acc[rr][cc], a2v[cc], q);
        }
        ps[rr] = p; qs[rr] = q;
    }
    #pragma unroll
    for (int off = 1; off <= 16; off <<= 1) {
        #pragma unroll
        for (int rr = 0; rr < 4; ++rr) {
            ps[rr] += __shfl_xor(ps[rr], off);
            qs[rr] += __shfl_xor(qs[rr], off);
        }
    }
    if (cg == 0) {
        #pragma unroll
        for (int rr = 0; rr < 4; ++rr) {
            si[r0 + rg * 4 + rr] = ps[rr];
            sj[r0 + rg * 4 + rr] = qs[rr];
            sjl[r0 + rg * 4 + rr] = qs[rr] * LOG2E;
        }
    }
    #pragma unroll
    for (int cc = 0; cc < 4; ++cc) {
        ushort4 v;
        v.x = f2bf(acc[0][cc]); v.y = f2bf(acc[1][cc]);
        v.z = f2bf(acc[2][cc]); v.w = f2bf(acc[3][cc]);
        *(ushort4*)(WhT + (size_t)(cg * 4 + cc) * NN + r0 + rg * 4) = v;
    }
}

// ---------------- K1s: sjmax = max_j sj[j] (global, one scalar) ----------------
__global__ __launch_bounds__(256) void gat_k1s(
    const float* __restrict__ sj, float* __restrict__ sjmax)
{
    __shared__ float red[256];
    float m = -1e30f;
    for (int i = threadIdx.x; i < NN; i += 256) m = fmaxf(m, sj[i]);
    red[threadIdx.x] = m;
    __syncthreads();
    for (int o = 128; o > 0; o >>= 1) {
        if (threadIdx.x < o) red[threadIdx.x] = fmaxf(red[threadIdx.x], red[threadIdx.x + o]);
        __syncthreads();
    }
    if (threadIdx.x == 0) sjmax[0] = red[0];
}

// ---------------- K2: fixed-m masked softmax (exp2 domain) + P@Wh via MFMA ----------------
// p = 2^( max(a2 + sjl, 0.2*sjl + b2) ) masked; a2=(si-m)*log2e, b2=(0.2*si-m)*log2e.
static __device__ __forceinline__ float pe(int av, float sjlv, float a2, float b2) {
    float t1 = a2 + sjlv;
    float t2 = fmaf(0.2f, sjlv, b2);
    float y = fmaxf(t1, t2);
    y = (av > 0) ? y : NEGB;      // 2^NEGB -> 0
    return ex2(y);
}

template<int JS, bool FINAL>
__global__ __launch_bounds__(256, 2) void gat_k2(
    const int* __restrict__ adj, const unsigned short* __restrict__ WhT,
    const float* __restrict__ si, const float* __restrict__ sjl,
    const float* __restrict__ sjmaxp,
    float* __restrict__ lsum, float* __restrict__ Opart, float* __restrict__ out)
{
    const int JR_ = NN / JS;
    const int NST_ = JR_ / BKJ;
    __shared__ __align__(16) unsigned short tile[2][16384];   // 2 x 32 KB WhT tile [128c][128j], XOR-swizzled
    const int t = threadIdx.x;
    const int w = t >> 6, l = t & 63;
    const int rb = (int)blockIdx.x / JS, js = (int)blockIdx.x % JS;
    const int iw = rb * 64 + w * 16;       // wave's 16 rows
    const int j0 = js * JR_;
    const int row = l & 15, kg = l >> 4;   // MFMA A-frag: row = l&15, k-slice = kg*8..+8

    const float si_l = si[iw + row];
    const float sjmax = sjmaxp[0];
    const float xm = si_l + sjmax;
    const float m_row = fmaxf(xm, LALPHA * xm);   // upper bound on every masked score of this row
    const float a2 = (si_l - m_row) * LOG2E;
    const float b2 = (LALPHA * si_l - m_row) * LOG2E;
    const float* sjb = sjl + j0 + kg * 8;
    const int* adjb = adj + (size_t)(iw + row) * NN + j0 + kg * 8;

    // staging: lane t covers WhT col c=v*16+(t>>4), 16B j-chunk ch=t&15; swz = (c&7)<<4
#define GSRC_D(v) const unsigned short* gsrc##v = WhT + (size_t)(v * 16 + (t >> 4)) * NN + j0 + (t & 15) * 8; \
                  const int ldo##v = ((v * 256 + t) * 16) ^ (((t >> 4) & 7) << 4);
    FOR8(GSRC_D)

#define REG_D(v) int4 stg##v, adr##v;
    FOR8(REG_D)
#define STG_L0(v) stg##v = *(const int4*)(gsrc##v);
    FOR8(STG_L0)
#define ADR_L0(q) adr##q = *(const int4*)(adjb + (q / 2) * 32 + (q % 2) * 4);
    FOR8(ADR_L0)

#define ACC_D(n) f32x4 acc##n = {0.f, 0.f, 0.f, 0.f};
    FOR8(ACC_D)
    f32x4 acc8 = {0.f, 0.f, 0.f, 0.f};    // row-sum accumulator (ones-MFMA)
    bf16x8 ones;
    #pragma unroll
    for (int z = 0; z < 8; ++z) ones[z] = (short)0x3F80;   // bf16 1.0
    const int kg16 = kg * 16;

#define STG_WR(v) *(int4*)((char*)tb + ldo##v) = stg##v;
#define STG_LN(v) stg##v = *(const int4*)(gsrc##v + so);
#define ADR_LN(q) adr##q = *(const int4*)(adjb + so + (q / 2) * 32 + (q % 2) * 4);
#define P8(AF, A0, A1, sp) { \
    float4 s0_ = *(const float4*)(sp); float4 s1_ = *(const float4*)((sp) + 4); \
    float p0_ = pe(A0.x, s0_.x, a2, b2), p1_ = pe(A0.y, s0_.y, a2, b2); \
    float p2_ = pe(A0.z, s0_.z, a2, b2), p3_ = pe(A0.w, s0_.w, a2, b2); \
    float p4_ = pe(A1.x, s1_.x, a2, b2), p5_ = pe(A1.y, s1_.y, a2, b2); \
    float p6_ = pe(A1.z, s1_.z, a2, b2), p7_ = pe(A1.w, s1_.w, a2, b2); \
    int4 w_; w_.x = cvtpk(p0_, p1_); w_.y = cvtpk(p2_, p3_); \
    w_.z = cvtpk(p4_, p5_); w_.w = cvtpk(p6_, p7_); \
    AF = __builtin_bit_cast(bf16x8, w_); }
#define MFMA_ROW(n) { const int c_ = n * 16 + row; \
    const int off_ = c_ * 256 + ((KB ^ ((c_ & 7) << 4))); \
    bf16x8 bv_ = *(const bf16x8*)((const char*)tb + off_); \
    acc##n = __builtin_amdgcn_mfma_f32_16x16x32_bf16(AFk, bv_, acc##n, 0, 0, 0); }
#define MFMA_KC(afv, kcl) { const bf16x8 AFk = afv; const int KB = kcl * 64 + kg16; FOR8(MFMA_ROW) \
    acc8 = __builtin_amdgcn_mfma_f32_16x16x32_bf16(AFk, ones, acc8, 0, 0, 0); }

    #pragma unroll 1   /* I$ hypothesis: keep the ~6KB step body loop-resident, not unrolled */
    for (int s = 0; s < NST_; ++s) {
        unsigned short* tb = tile[s & 1];
        // A: scores -> p (bf16) first (adj for step s arrived a full step ago)
        bf16x8 af0, af1, af2, af3;
        {
            const float* spp = sjb + s * BKJ;
            P8(af0, adr0, adr1, spp)
            P8(af1, adr2, adr3, spp + 32)
            P8(af2, adr4, adr5, spp + 64)
            P8(af3, adr6, adr7, spp + 96)
        }
        // B: issue next adj loads NOW (full-step lead to cover HBM drain)
        if (s + 1 < NST_) {
            const size_t so = (size_t)(s + 1) * BKJ;
            FOR8(ADR_LN)
        }
        // C: write staged WhT tile (swizzled b128 writes)
        FOR8(STG_WR)
        // D: issue next WhT stage loads (L2-fast)
        if (s + 1 < NST_) {
            const size_t so = (size_t)(s + 1) * BKJ;
            FOR8(STG_LN)
        }
        // E: lgkm-only barrier — do NOT drain the in-flight global prefetches
        __builtin_amdgcn_sched_barrier(0);
        asm volatile("s_waitcnt lgkmcnt(0)" ::: "memory");
        __builtin_amdgcn_s_barrier();
        __builtin_amdgcn_sched_barrier(0);
        // F: MFMA 4 k-chunks x (8 col-tiles + 1 ones row-sum)
        MFMA_KC(af0, 0) MFMA_KC(af1, 1) MFMA_KC(af2, 2) MFMA_KC(af3, 3)
    }

    // acc8[q] = rowsum for row iw + kg*4 + q (identical across the 16 col-lanes)
    if (FINAL) {
#define FN_ROW(n) { size_t ob = (size_t)(iw + kg * 4) * FOUT + n * 16 + row; \
    float o0 = acc##n[0] / acc8[0]; out[ob]            = (o0 > 0.f) ? o0 : expm1f(o0); \
    float o1 = acc##n[1] / acc8[1]; out[ob + FOUT]     = (o1 > 0.f) ? o1 : expm1f(o1); \
    float o2 = acc##n[2] / acc8[2]; out[ob + 2 * FOUT] = (o2 > 0.f) ? o2 : expm1f(o2); \
    float o3 = acc##n[3] / acc8[3]; out[ob + 3 * FOUT] = (o3 > 0.f) ? o3 : expm1f(o3); }
        FOR8(FN_ROW)
    } else {
        if (row == 0) {
            #pragma unroll
            for (int q = 0; q < 4; ++q)
                lsum[(size_t)js * NN + iw + kg * 4 + q] = acc8[q];
        }
#define ST_ROW(n) { size_t ob = ((size_t)js * NN + iw + kg * 4) * FOUT + n * 16 + row; \
    Opart[ob] = acc##n[0]; Opart[ob + FOUT] = acc##n[1]; \
    Opart[ob + 2 * FOUT] = acc##n[2]; Opart[ob + 3 * FOUT] = acc##n[3]; }
        FOR8(ST_ROW)
    }
}

// ---------------- K3: merge j-splits (plain sums; shared fixed m), divide, ELU ----------------
__global__ __launch_bounds__(256) void gat_k3(
    const float* __restrict__ lsum, const float* __restrict__ Opart,
    float* __restrict__ out)
{
    const int t = threadIdx.x;
    const int i = (int)blockIdx.x * 2 + (t >> 7);
    const int f = t & 127;
    float den = 0.f, num = 0.f;
    const size_t SP = (size_t)NN * FOUT;
    size_t base = (size_t)i * FOUT + f;
    #pragma unroll
    for (int k = 0; k < JSPLIT; ++k) {
        den += lsum[(size_t)k * NN + i];
        num += Opart[(size_t)k * SP + base];
    }
    float o = num / den;
    out[base] = (o > 0.f) ? o : expm1f(o);   // ELU, alpha=1
}

extern "C" void kernel_launch(void* const* d_in, const int* in_sizes, int n_in,
                              void* d_out, int out_size, void* d_ws, size_t ws_size,
                              hipStream_t stream) {
    const float* h  = (const float*)d_in[0];
    const int*  adj = (const int*)d_in[1];
    const float* W  = (const float*)d_in[2];
    const float* a  = (const float*)d_in[3];
    float* out = (float*)d_out;
    char* ws = (char*)d_ws;
    // ws: WhT 2MB | si 32KB | sj 32KB | sjl 32KB | sjmax 256B | lsum 4*32KB | Opart 4*4MB
    unsigned short* WhT = (unsigned short*)ws;
    float* si     = (float*)(ws + 2097152);
    float* sj     = (float*)(ws + 2129920);
    float* sjl    = (float*)(ws + 2162688);
    float* sjmax  = (float*)(ws + 2195456);
    float* lsum   = (float*)(ws + 2195712);
    float* Opart  = (float*)(ws + 2326784);
    const size_t need = 2326784 + (size_t)JSPLIT * NN * FOUT * 4;   // ~19.1 MB

    gat_k1<<<256, 256, 0, stream>>>(h, W, a, WhT, si, sj, sjl);
    gat_k1s<<<1, 256, 0, stream>>>(sj, sjmax);
    if (ws_size >= need) {
        gat_k2<JSPLIT, false><<<128 * JSPLIT, 256, 0, stream>>>(adj, WhT, si, sjl, sjmax, lsum, Opart, out);
        gat_k3<<<4096, 256, 0, stream>>>(lsum, Opart, out);
    } else {
        gat_k2<1, true><<<128, 256, 0, stream>>>(adj, WhT, si, sjl, sjmax, lsum, Opart, out);
    }
}

// Round 15
// 101.573 us; speedup vs baseline: 3.0234x; 1.0163x over previous
//
#include <hip/hip_runtime.h>

#define NN 8192
#define FIN 256
#define FOUT 128
#define BKJ 128            /* j per step */
#define JSPLIT 8
#define LALPHA 0.2f
#define NEGB -9.0e15f
#define LOG2E 1.4426950408889634f

typedef short bf16x8 __attribute__((ext_vector_type(8)));
typedef float f32x4 __attribute__((ext_vector_type(4)));

#define FOR8(X) X(0) X(1) X(2) X(3) X(4) X(5) X(6) X(7)

static __device__ __forceinline__ unsigned short f2bf(float f) {
    unsigned u = __float_as_uint(f);
    u += 0x7FFFu + ((u >> 16) & 1u);   // RNE
    return (unsigned short)(u >> 16);
}
static __device__ __forceinline__ float ex2(float x) {
    float r; asm("v_exp_f32 %0, %1" : "=v"(r) : "v"(x)); return r;
}
static __device__ __forceinline__ int cvtpk(float lo, float hi) {
    int r; asm("v_cvt_pk_bf16_f32 %0, %1, %2" : "=v"(r) : "v"(lo), "v"(hi)); return r;
}

// ---------------- K1: Wh = h@W (f32), si = Wh@a1, sj = Wh@a2 (+sjl = sj*log2e), WhT bf16 ----------------
__global__ __launch_bounds__(256) void gat_k1(
    const float* __restrict__ h, const float* __restrict__ W,
    const float* __restrict__ a, unsigned short* __restrict__ WhT,
    float* __restrict__ si, float* __restrict__ sj, float* __restrict__ sjl)
{
    __shared__ float Wt[64 * 128];          // 32 KB: W chunk [64k][128c]
    __shared__ float hT[64 * 36 + 4];       // 9 KB: h chunk transposed [64k][32r] pad 36
    const int t = threadIdx.x;
    const int r0 = blockIdx.x * 32;
    const int rg = t >> 5;    // rows rg*4..+4
    const int cg = t & 31;    // cols cg*4..+4
    float acc[4][4] = {{0.f,0.f,0.f,0.f},{0.f,0.f,0.f,0.f},{0.f,0.f,0.f,0.f},{0.f,0.f,0.f,0.f}};

    for (int kc = 0; kc < 4; ++kc) {
        __syncthreads();
        const float4* Ws = (const float4*)(W + kc * 64 * FOUT);
        float4* Wd = (float4*)Wt;
        #pragma unroll
        for (int v = 0; v < 8; ++v) Wd[v * 256 + t] = Ws[v * 256 + t];
        {
            const int hr = t >> 3, hk = (t & 7) * 8;
            const float* hs = h + (size_t)(r0 + hr) * FIN + kc * 64 + hk;
            float4 x0 = *(const float4*)hs;
            float4 x1 = *(const float4*)(hs + 4);
            hT[(hk + 0) * 36 + hr] = x0.x; hT[(hk + 1) * 36 + hr] = x0.y;
            hT[(hk + 2) * 36 + hr] = x0.z; hT[(hk + 3) * 36 + hr] = x0.w;
            hT[(hk + 4) * 36 + hr] = x1.x; hT[(hk + 5) * 36 + hr] = x1.y;
            hT[(hk + 6) * 36 + hr] = x1.z; hT[(hk + 7) * 36 + hr] = x1.w;
        }
        __syncthreads();
        #pragma unroll 8
        for (int kk = 0; kk < 64; ++kk) {
            float4 hv4 = *(const float4*)&hT[kk * 36 + rg * 4];
            float4 wv4 = *(const float4*)&Wt[kk * 128 + cg * 4];
            float hv[4] = {hv4.x, hv4.y, hv4.z, hv4.w};
            float wv[4] = {wv4.x, wv4.y, wv4.z, wv4.w};
            #pragma unroll
            for (int rr = 0; rr < 4; ++rr)
                #pragma unroll
                for (int cc = 0; cc < 4; ++cc)
                    acc[rr][cc] = fmaf(hv[rr], wv[cc], acc[rr][cc]);
        }
    }
    float4 a1v4 = *(const float4*)(a + cg * 4);
    float4 a2v4 = *(const float4*)(a + FOUT + cg * 4);
    float a1v[4] = {a1v4.x, a1v4.y, a1v4.z, a1v4.w};
    float a2v[4] = {a2v4.x, a2v4.y, a2v4.z, a2v4.w};
    float ps[4], qs[4];
    #pragma unroll
    for (int rr = 0; rr < 4; ++rr) {
        float p = 0.f, q = 0.f;
        #pragma unroll
        for (int cc = 0; cc < 4; ++cc) {
            p = fmaf(acc[rr][cc], a1v[cc], p);
            q = fmaf(acc[rr][cc], a2v[cc], q);
        }
        ps[rr] = p; qs[rr] = q;
    }
    #pragma unroll
    for (int off = 1; off <= 16; off <<= 1) {
        #pragma unroll
        for (int rr = 0; rr < 4; ++rr) {
            ps[rr] += __shfl_xor(ps[rr], off);
            qs[rr] += __shfl_xor(qs[rr], off);
        }
    }
    if (cg == 0) {
        #pragma unroll
        for (int rr = 0; rr < 4; ++rr) {
            si[r0 + rg * 4 + rr] = ps[rr];
            sj[r0 + rg * 4 + rr] = qs[rr];
            sjl[r0 + rg * 4 + rr] = qs[rr] * LOG2E;
        }
    }
    #pragma unroll
    for (int cc = 0; cc < 4; ++cc) {
        ushort4 v;
        v.x = f2bf(acc[0][cc]); v.y = f2bf(acc[1][cc]);
        v.z = f2bf(acc[2][cc]); v.w = f2bf(acc[3][cc]);
        *(ushort4*)(WhT + (size_t)(cg * 4 + cc) * NN + r0 + rg * 4) = v;
    }
}

// ---------------- K1s: sjmax = max_j sj[j] (global, one scalar) ----------------
__global__ __launch_bounds__(256) void gat_k1s(
    const float* __restrict__ sj, float* __restrict__ sjmax)
{
    __shared__ float red[256];
    float m = -1e30f;
    for (int i = threadIdx.x; i < NN; i += 256) m = fmaxf(m, sj[i]);
    red[threadIdx.x] = m;
    __syncthreads();
    for (int o = 128; o > 0; o >>= 1) {
        if (threadIdx.x < o) red[threadIdx.x] = fmaxf(red[threadIdx.x], red[threadIdx.x + o]);
        __syncthreads();
    }
    if (threadIdx.x == 0) sjmax[0] = red[0];
}

// ---------------- K2: fixed-m masked softmax (exp2) + P@Wh via MFMA, 2 row-tiles/wave ----------------
// Block = 128 rows x JR j-slice; 4 waves x 32 rows. Each B-fragment read feeds 2 MFMAs
// (row-tiles A and B) -> LDS read bytes per output halved vs 16-row waves.
static __device__ __forceinline__ float pe(int av, float sjlv, float a2, float b2) {
    float t1 = a2 + sjlv;
    float t2 = fmaf(0.2f, sjlv, b2);
    float y = fmaxf(t1, t2);
    y = (av > 0) ? y : NEGB;      // 2^NEGB -> 0
    return ex2(y);
}

template<int JS, bool FINAL>
__global__ __launch_bounds__(256, 2) void gat_k2(
    const int* __restrict__ adj, const unsigned short* __restrict__ WhT,
    const float* __restrict__ si, const float* __restrict__ sjl,
    const float* __restrict__ sjmaxp,
    float* __restrict__ lsum, float* __restrict__ Opart, float* __restrict__ out)
{
    const int JR_ = NN / JS;
    const int NST_ = JR_ / BKJ;
    __shared__ __align__(16) unsigned short tile[2][16384];   // 2 x 32 KB WhT tile [128c][128j], XOR-swizzled
    __shared__ __align__(16) float sjl_lds[NN / JS];          // block's sjl slice
    const int t = threadIdx.x;
    const int w = t >> 6, l = t & 63;
    const int rb = (int)blockIdx.x / JS, js = (int)blockIdx.x % JS;
    const int iw0 = rb * 128 + w * 32;     // wave's row-tile A (16 rows)
    const int iw1 = iw0 + 16;              // wave's row-tile B
    const int j0 = js * JR_;
    const int row = l & 15, kg = l >> 4;   // A-frag: row=l&15, k-slice=kg*8..+8
    const int kg8 = kg * 8;

    const float sjmax = sjmaxp[0];
    const float si_l0 = si[iw0 + row];
    const float si_l1 = si[iw1 + row];
    const float xm0 = si_l0 + sjmax, xm1 = si_l1 + sjmax;
    const float m0 = fmaxf(xm0, LALPHA * xm0), m1 = fmaxf(xm1, LALPHA * xm1);
    const float a2A = (si_l0 - m0) * LOG2E, b2A = (LALPHA * si_l0 - m0) * LOG2E;
    const float a2B = (si_l1 - m1) * LOG2E, b2B = (LALPHA * si_l1 - m1) * LOG2E;
    const int* adjb0 = adj + (size_t)(iw0 + row) * NN + j0 + kg8;
    const int* adjb1 = adj + (size_t)(iw1 + row) * NN + j0 + kg8;

    // prologue: sjl slice -> LDS (broadcast-read later)
    for (int i = t * 4; i < JR_; i += 1024)
        *(float4*)&sjl_lds[i] = *(const float4*)(sjl + j0 + i);

    // staging: lane t covers WhT col c=v*16+(t>>4), 16B j-chunk ch=t&15; swz = (c&7)<<4
#define GSRC_D(v) const unsigned short* gsrc##v = WhT + (size_t)(v * 16 + (t >> 4)) * NN + j0 + (t & 15) * 8; \
                  const int ldo##v = ((v * 256 + t) * 16) ^ (((t >> 4) & 7) << 4);
    FOR8(GSRC_D)

#define REG_D(v) int4 stg##v, adrA##v, adrB##v;
    FOR8(REG_D)
#define STG_L0(v) stg##v = *(const int4*)(gsrc##v);
    FOR8(STG_L0)
#define ADR_L0(q) adrA##q = *(const int4*)(adjb0 + (q / 2) * 32 + (q % 2) * 4); \
                  adrB##q = *(const int4*)(adjb1 + (q / 2) * 32 + (q % 2) * 4);
    FOR8(ADR_L0)

#define ACC_D(n) f32x4 accA##n = {0.f, 0.f, 0.f, 0.f}; f32x4 accB##n = {0.f, 0.f, 0.f, 0.f};
    FOR8(ACC_D)
    f32x4 acc8A = {0.f, 0.f, 0.f, 0.f};   // row-sum accumulators (ones-MFMA)
    f32x4 acc8B = {0.f, 0.f, 0.f, 0.f};
    bf16x8 ones;
    #pragma unroll
    for (int z = 0; z < 8; ++z) ones[z] = (short)0x3F80;   // bf16 1.0
    const int kg16 = kg * 16;

    __syncthreads();   // sjl_lds ready

#define STG_WR(v) *(int4*)((char*)tb + ldo##v) = stg##v;
#define STG_LN(v) stg##v = *(const int4*)(gsrc##v + so);
#define ADR_LN(q) adrA##q = *(const int4*)(adjb0 + so + (q / 2) * 32 + (q % 2) * 4); \
                  adrB##q = *(const int4*)(adjb1 + so + (q / 2) * 32 + (q % 2) * 4);
#define P8(AF, A0, A1, off, A2C, B2C) { \
    float4 s0_ = *(const float4*)&sjl_lds[(off)]; float4 s1_ = *(const float4*)&sjl_lds[(off) + 4]; \
    float p0_ = pe(A0.x, s0_.x, A2C, B2C), p1_ = pe(A0.y, s0_.y, A2C, B2C); \
    float p2_ = pe(A0.z, s0_.z, A2C, B2C), p3_ = pe(A0.w, s0_.w, A2C, B2C); \
    float p4_ = pe(A1.x, s1_.x, A2C, B2C), p5_ = pe(A1.y, s1_.y, A2C, B2C); \
    float p6_ = pe(A1.z, s1_.z, A2C, B2C), p7_ = pe(A1.w, s1_.w, A2C, B2C); \
    int4 w_; w_.x = cvtpk(p0_, p1_); w_.y = cvtpk(p2_, p3_); \
    w_.z = cvtpk(p4_, p5_); w_.w = cvtpk(p6_, p7_); \
    AF = __builtin_bit_cast(bf16x8, w_); }
    // B-read once, feed both row-tiles
#define MFMA_N(n) { const int c_ = n * 16 + row; \
    const int off_ = c_ * 256 + ((KB ^ ((c_ & 7) << 4))); \
    bf16x8 bv_ = *(const bf16x8*)((const char*)tb + off_); \
    accA##n = __builtin_amdgcn_mfma_f32_16x16x32_bf16(AFa, bv_, accA##n, 0, 0, 0); \
    accB##n = __builtin_amdgcn_mfma_f32_16x16x32_bf16(AFb, bv_, accB##n, 0, 0, 0); }
#define MFMA_KC2(afa, afb, kcl) { const bf16x8 AFa = afa, AFb = afb; const int KB = kcl * 64 + kg16; FOR8(MFMA_N) \
    acc8A = __builtin_amdgcn_mfma_f32_16x16x32_bf16(AFa, ones, acc8A, 0, 0, 0); \
    acc8B = __builtin_amdgcn_mfma_f32_16x16x32_bf16(AFb, ones, acc8B, 0, 0, 0); }

    for (int s = 0; s < NST_; ++s) {
        unsigned short* tb = tile[s & 1];
        // A: scores -> p (bf16) for both row-tiles (adj arrived a full step ago)
        bf16x8 afA0, afA1, afA2, afA3, afB0, afB1, afB2, afB3;
        {
            const int off = s * BKJ + kg8;
            P8(afA0, adrA0, adrA1, off,      a2A, b2A)
            P8(afA1, adrA2, adrA3, off + 32, a2A, b2A)
            P8(afA2, adrA4, adrA5, off + 64, a2A, b2A)
            P8(afA3, adrA6, adrA7, off + 96, a2A, b2A)
            P8(afB0, adrB0, adrB1, off,      a2B, b2B)
            P8(afB1, adrB2, adrB3, off + 32, a2B, b2B)
            P8(afB2, adrB4, adrB5, off + 64, a2B, b2B)
            P8(afB3, adrB6, adrB7, off + 96, a2B, b2B)
        }
        // B: issue next adj loads (full-step lead covers HBM latency)
        if (s + 1 < NST_) {
            const size_t so = (size_t)(s + 1) * BKJ;
            FOR8(ADR_LN)
        }
        // C: write staged WhT tile (swizzled b128 writes)
        FOR8(STG_WR)
        // D: issue next WhT stage loads (L2-fast)
        if (s + 1 < NST_) {
            const size_t so = (size_t)(s + 1) * BKJ;
            FOR8(STG_LN)
        }
        // E: lgkm-only barrier — keep global prefetches in flight
        __builtin_amdgcn_sched_barrier(0);
        asm volatile("s_waitcnt lgkmcnt(0)" ::: "memory");
        __builtin_amdgcn_s_barrier();
        __builtin_amdgcn_sched_barrier(0);
        // F: MFMA 4 k-chunks x 8 col-tiles; each B-frag feeds 2 row-tiles (+2 ones row-sums)
        MFMA_KC2(afA0, afB0, 0) MFMA_KC2(afA1, afB1, 1)
        MFMA_KC2(afA2, afB2, 2) MFMA_KC2(afA3, afB3, 3)
    }

    // acc8{A,B}[q] = rowsum for row iw{0,1} + kg*4 + q (copies across the 16 col-lanes)
    if (FINAL) {
#define FN_ROW(n) { \
    size_t obA = (size_t)(iw0 + kg * 4) * FOUT + n * 16 + row; \
    size_t obB = (size_t)(iw1 + kg * 4) * FOUT + n * 16 + row; \
    _Pragma("unroll") for (int r = 0; r < 4; ++r) { \
        float oA = accA##n[r] / acc8A[r]; out[obA + (size_t)r * FOUT] = (oA > 0.f) ? oA : expm1f(oA); \
        float oB = accB##n[r] / acc8B[r]; out[obB + (size_t)r * FOUT] = (oB > 0.f) ? oB : expm1f(oB); } }
        FOR8(FN_ROW)
    } else {
        if (row == 0) {
            #pragma unroll
            for (int q = 0; q < 4; ++q) {
                lsum[(size_t)js * NN + iw0 + kg * 4 + q] = acc8A[q];
                lsum[(size_t)js * NN + iw1 + kg * 4 + q] = acc8B[q];
            }
        }
#define ST_ROW(n) { \
    size_t obA = ((size_t)js * NN + iw0 + kg * 4) * FOUT + n * 16 + row; \
    size_t obB = ((size_t)js * NN + iw1 + kg * 4) * FOUT + n * 16 + row; \
    _Pragma("unroll") for (int r = 0; r < 4; ++r) { \
        Opart[obA + (size_t)r * FOUT] = accA##n[r]; \
        Opart[obB + (size_t)r * FOUT] = accB##n[r]; } }
        FOR8(ST_ROW)
    }
}

// ---------------- K3: merge j-splits (plain sums; shared fixed m), divide, ELU ----------------
__global__ __launch_bounds__(256) void gat_k3(
    const float* __restrict__ lsum, const float* __restrict__ Opart,
    float* __restrict__ out)
{
    const int t = threadIdx.x;
    const int i = (int)blockIdx.x * 2 + (t >> 7);
    const int f = t & 127;
    float den = 0.f, num = 0.f;
    const size_t SP = (size_t)NN * FOUT;
    size_t base = (size_t)i * FOUT + f;
    #pragma unroll
    for (int k = 0; k < JSPLIT; ++k) {
        den += lsum[(size_t)k * NN + i];
        num += Opart[(size_t)k * SP + base];
    }
    float o = num / den;
    out[base] = (o > 0.f) ? o : expm1f(o);   // ELU, alpha=1
}

extern "C" void kernel_launch(void* const* d_in, const int* in_sizes, int n_in,
                              void* d_out, int out_size, void* d_ws, size_t ws_size,
                              hipStream_t stream) {
    const float* h  = (const float*)d_in[0];
    const int*  adj = (const int*)d_in[1];
    const float* W  = (const float*)d_in[2];
    const float* a  = (const float*)d_in[3];
    float* out = (float*)d_out;
    char* ws = (char*)d_ws;
    // ws: WhT 2MB | si 32KB | sj 32KB | sjl 32KB | sjmax 256B | lsum 8*32KB | Opart 8*4MB
    unsigned short* WhT = (unsigned short*)ws;
    float* si     = (float*)(ws + 2097152);
    float* sj     = (float*)(ws + 2129920);
    float* sjl    = (float*)(ws + 2162688);
    float* sjmax  = (float*)(ws + 2195456);
    float* lsum   = (float*)(ws + 2195712);
    float* Opart  = (float*)(ws + 2457856);
    const size_t need = 2457856 + (size_t)JSPLIT * NN * FOUT * 4;   // ~36 MB

    gat_k1<<<256, 256, 0, stream>>>(h, W, a, WhT, si, sj, sjl);
    gat_k1s<<<1, 256, 0, stream>>>(sj, sjmax);
    if (ws_size >= need) {
        gat_k2<JSPLIT, false><<<64 * JSPLIT, 256, 0, stream>>>(adj, WhT, si, sjl, sjmax, lsum, Opart, out);
        gat_k3<<<4096, 256, 0, stream>>>(lsum, Opart, out);
    } else {
        gat_k2<1, true><<<64, 256, 0, stream>>>(adj, WhT, si, sjl, sjmax, lsum, Opart, out);
    }
}